// Round 8
// baseline (1436.706 us; speedup 1.0000x reference)
//
#include <hip/hip_runtime.h>
#include <math.h>

#define T_STEPS 8
#define N_NODES 20000
#define F_IN    128
#define H_DIM   256
#define E_EDGES 320000

#define G_UPD    625     // update tiles (20000/32)
#define G_AGG    5000    // 625 node-groups x 8 col-chunks
#define NC32     ((size_t)N_NODES * 32)   // elems per chunk-major slice

typedef __attribute__((ext_vector_type(8))) short short8;
typedef __attribute__((ext_vector_type(4))) short s16x4;
typedef __attribute__((ext_vector_type(4))) unsigned short us4;
typedef __attribute__((ext_vector_type(4))) float f32x4;

__device__ __forceinline__ void split2(float v, unsigned short& h, unsigned short& l) {
    unsigned vi = __float_as_uint(v);
    h = (unsigned short)(vi >> 16);
    float hf = __uint_as_float(vi & 0xffff0000u);
    l = (unsigned short)(__float_as_uint(v - hf) >> 16);
}

__device__ __forceinline__ float bf2f(unsigned short h) {
    return __uint_as_float((unsigned)h << 16);
}

// ---------------- CSR build ----------------

__global__ void count_kernel(const int* __restrict__ dst, int* __restrict__ counts, int E) {
    int e = blockIdx.x * blockDim.x + threadIdx.x;
    if (e < E) atomicAdd(&counts[dst[e]], 1);
}

__global__ void scan_kernel(const int* __restrict__ counts, int* __restrict__ row_ptr,
                            int* __restrict__ cursors, int n) {
    __shared__ int buf[1024];
    __shared__ int carry_s;
    int tid = threadIdx.x;
    if (tid == 0) carry_s = 0;
    __syncthreads();
    for (int base = 0; base < n; base += 1024) {
        int i = base + tid;
        int v = (i < n) ? counts[i] : 0;
        buf[tid] = v;
        __syncthreads();
        for (int off = 1; off < 1024; off <<= 1) {
            int t = (tid >= off) ? buf[tid - off] : 0;
            __syncthreads();
            buf[tid] += t;
            __syncthreads();
        }
        int incl = buf[tid];
        int carry = carry_s;
        if (i < n) {
            int ex = carry + incl - v;
            row_ptr[i] = ex;
            cursors[i] = ex;
        }
        __syncthreads();
        if (tid == 1023) carry_s = carry + incl;
        __syncthreads();
    }
    if (tid == 0) row_ptr[n] = carry_s;
}

__global__ void fill_kernel(const int* __restrict__ src, const int* __restrict__ dst,
                            int* __restrict__ cursors, unsigned short* __restrict__ col, int E) {
    int e = blockIdx.x * blockDim.x + threadIdx.x;
    if (e < E) {
        int d = dst[e];
        int p = atomicAdd(&cursors[d], 1);
        col[p] = (unsigned short)src[e];
    }
}

// ---------------- weight fp32 -> MFMA-fragment-major bf16 hi/lo ----------------

__global__ void cvt_frag(const float* __restrict__ W, int K,
                         unsigned short* __restrict__ fh, unsigned short* __restrict__ fl) {
    int g = blockIdx.x * 256 + threadIdx.x;
    int KP32 = K >> 5;
    int total = (H_DIM / 16) * KP32 * 64;
    if (g >= total) return;
    int lane = g & 63;
    int kp = (g >> 6) % KP32;
    int rt = g / (KP32 << 6);
    int r = rt * 16 + (lane & 15);
    int c = kp * 32 + (lane >> 4) * 8;
    const float* p = W + (size_t)r * K + c;
    short8 h, l;
    #pragma unroll
    for (int j = 0; j < 8; ++j) {
        unsigned short hh, ll;
        split2(p[j], hh, ll);
        h[j] = (short)hh; l[j] = (short)ll;
    }
    *(short8*)(fh + (size_t)g * 8) = h;
    *(short8*)(fl + (size_t)g * 8) = l;
}

// ---------------- f32 -> bf16 hi/lo row-major split (one-time, for x) ----------------

__global__ void cvt_split(const float* __restrict__ src, unsigned short* __restrict__ dh,
                          unsigned short* __restrict__ dl, int total4) {
    int g = blockIdx.x * 256 + threadIdx.x;
    if (g >= total4) return;
    float4 v = *(const float4*)(src + (size_t)g * 4);
    us4 h, l;
    unsigned short hh, ll;
    split2(v.x, hh, ll); h[0] = hh; l[0] = ll;
    split2(v.y, hh, ll); h[1] = hh; l[1] = ll;
    split2(v.z, hh, ll); h[2] = hh; l[2] = ll;
    split2(v.w, hh, ll); h[3] = hh; l[3] = ll;
    *(us4*)(dh + (size_t)g * 4) = h;
    *(us4*)(dl + (size_t)g * 4) = l;
}

// ---------------- gather kernel: int16 Q15 source, bf16 hi/lo output ----------------
// r6: gather rate invariant to tier/ILP/layout with all pipes <30% -> per-CU
// line-initiation cap; lever = fewer lines/bytes. r7 tried fp16 (64 B/edge-
// chunk) -> accuracy fail: fp16 ulp 4.9e-4 x degree ~40 x 8-step compounding
// = 0.044 > 0.02. r8: int16 Q15 (state provably in (-1,1)) -> same 64 B but
// quant err 1.5e-5 (32x better) and EXACT int32 accumulation. AGG output
// directly as bf16 hi/lo row-major (what UPD part-2 consumes).
// Structure from r5/r6: 8 concurrent row chains; chunk = b&7 XCD pin;
// dual-buffer mode at grid 2*G_AGG.

__global__ __launch_bounds__(256) void agg_kernel(
        const short* __restrict__ gsrcA,
        unsigned short* __restrict__ goAh, unsigned short* __restrict__ goAl,
        const short* __restrict__ gsrcB,
        unsigned short* __restrict__ goBh, unsigned short* __restrict__ goBl,
        const int* __restrict__ row_ptr, const unsigned short* __restrict__ col) {
    int b = blockIdx.x;
    const short* gsrc = gsrcA;
    unsigned short* goh = goAh;
    unsigned short* gol = goAl;
    if (b >= G_AGG) { b -= G_AGG; gsrc = gsrcB; goh = goBh; gol = goBl; }
    const int tid = threadIdx.x;
    const int lane = tid & 63, w = tid >> 6;
    const int chunk = b & 7;       // XCD pin
    const int nb = b >> 3;
    const int slot = lane >> 3, comp = lane & 7;   // comp -> cols comp*4..+4
    const s16x4* src4 = (const s16x4*)(gsrc + (size_t)chunk * NC32) + comp;
    const int r0 = nb * 32 + w * 8;

    int jj[8], en[8];
    int ac[8][4];
    #pragma unroll
    for (int k = 0; k < 8; ++k) {
        jj[k] = row_ptr[r0 + k] + slot;
        en[k] = row_ptr[r0 + k + 1];
        ac[k][0] = 0; ac[k][1] = 0; ac[k][2] = 0; ac[k][3] = 0;
    }
    while (true) {
        bool ok[8];
        int ix[8];
        bool anyv = false;
        #pragma unroll
        for (int k = 0; k < 8; ++k) {
            ok[k] = jj[k] < en[k];
            anyv |= ok[k];
            ix[k] = ok[k] ? jj[k] : 0;
        }
        if (!anyv) break;
        int cc[8];
        #pragma unroll
        for (int k = 0; k < 8; ++k) cc[k] = col[ix[k]];
        #pragma unroll
        for (int k = 0; k < 8; ++k) {
            s16x4 v = src4[(size_t)cc[k] * 8];   // node stride = 64 B = 8 s16x4
            if (ok[k]) {
                ac[k][0] += (int)v[0];
                ac[k][1] += (int)v[1];
                ac[k][2] += (int)v[2];
                ac[k][3] += (int)v[3];
                jj[k] += 8;
            }
        }
    }
    // cross-slot reduce (slots differ in lane bits 3..5); int adds, exact
    #pragma unroll
    for (int k = 0; k < 8; ++k) {
        #pragma unroll
        for (int m = 8; m < 64; m <<= 1) {
            ac[k][0] += __shfl_xor(ac[k][0], m);
            ac[k][1] += __shfl_xor(ac[k][1], m);
            ac[k][2] += __shfl_xor(ac[k][2], m);
            ac[k][3] += __shfl_xor(ac[k][3], m);
        }
    }
    if (slot == 0) {
        const float sc = 1.0f / 32768.0f;
        #pragma unroll
        for (int k = 0; k < 8; ++k) {
            us4 h, l;
            unsigned short hh, ll;
            split2((float)ac[k][0] * sc, hh, ll); h[0] = hh; l[0] = ll;
            split2((float)ac[k][1] * sc, hh, ll); h[1] = hh; l[1] = ll;
            split2((float)ac[k][2] * sc, hh, ll); h[2] = hh; l[2] = ll;
            split2((float)ac[k][3] * sc, hh, ll); h[3] = hh; l[3] = ll;
            size_t o = (size_t)(r0 + k) * H_DIM + chunk * 32 + comp * 4;
            *(us4*)(goh + o) = h;
            *(us4*)(gol + o) = l;
        }
    }
}

// ---------------- update kernel ----------------
// Dense MFMA update, 32 rows x 256 cols per block, 4 waves. All A operands
// (x, state, AGG) pre-stored as bf16 hi/lo row-major -> short8 loads feed the
// 3-pass MFMA directly (r4 post-mortem: split2 VALU chains were the stall;
// numerics identical: hi+lo == split2 of the f32 value). One-kp-ahead A
// prefetch. Epilogue: state out as hi/lo bf16 rm + int16 Q15 chunk-major
// (gather source) + optional f32 (d_out only).

__device__ __forceinline__ void upd_body(
        const unsigned short* __restrict__ Ahi, const unsigned short* __restrict__ Alo, int K1,
        const unsigned short* __restrict__ sphi, const unsigned short* __restrict__ splo,
        const unsigned short* __restrict__ B1h, const unsigned short* __restrict__ B1l,
        const unsigned short* __restrict__ B2h, const unsigned short* __restrict__ B2l,
        const unsigned short* __restrict__ AGh, const unsigned short* __restrict__ AGl,
        unsigned short* __restrict__ snhi, unsigned short* __restrict__ snlo,
        short* __restrict__ sncm, float* __restrict__ dout,
        const float* __restrict__ leak_ptr, int m0) {
    const int tid = threadIdx.x;
    const int lane = tid & 63, w = tid >> 6;
    const int fr = lane & 15, fq = lane >> 4;
    const int wn = w * 64;
    const int rtbase = w * 4;

    f32x4 acc[2][4];
    #pragma unroll
    for (int mi = 0; mi < 2; ++mi)
        #pragma unroll
        for (int nt = 0; nt < 4; ++nt)
            acc[mi][nt] = (f32x4){0.f, 0.f, 0.f, 0.f};

    // ---- part 1: A = Ahi/Alo (row-major bf16), prefetched ----
    {
        const int KP32 = K1 >> 5;
        const unsigned short* ah0p = Ahi + (size_t)(m0 + fr) * K1 + fq * 8;
        const unsigned short* ah1p = Ahi + (size_t)(m0 + 16 + fr) * K1 + fq * 8;
        const unsigned short* al0p = Alo + (size_t)(m0 + fr) * K1 + fq * 8;
        const unsigned short* al1p = Alo + (size_t)(m0 + 16 + fr) * K1 + fq * 8;
        short8 ah[2], al[2];
        ah[0] = *(const short8*)ah0p;
        ah[1] = *(const short8*)ah1p;
        al[0] = *(const short8*)al0p;
        al[1] = *(const short8*)al1p;
        #pragma unroll 1
        for (int kp = 0; kp < KP32; ++kp) {
            const int kpn = (kp + 1 < KP32) ? kp + 1 : kp;
            short8 nh0 = *(const short8*)(ah0p + kpn * 32);
            short8 nh1 = *(const short8*)(ah1p + kpn * 32);
            short8 nl0 = *(const short8*)(al0p + kpn * 32);
            short8 nl1 = *(const short8*)(al1p + kpn * 32);
            short8 bh[4], bl[4];
            #pragma unroll
            for (int nt = 0; nt < 4; ++nt) {
                size_t off = ((size_t)((rtbase + nt) * KP32 + kp) * 64 + lane) * 8;
                bh[nt] = *(const short8*)(B1h + off);
                bl[nt] = *(const short8*)(B1l + off);
            }
            #pragma unroll
            for (int mi = 0; mi < 2; ++mi)
                #pragma unroll
                for (int nt = 0; nt < 4; ++nt) {
                    f32x4 c = acc[mi][nt];
                    c = __builtin_amdgcn_mfma_f32_16x16x32_bf16(ah[mi], bh[nt], c, 0, 0, 0);
                    c = __builtin_amdgcn_mfma_f32_16x16x32_bf16(al[mi], bh[nt], c, 0, 0, 0);
                    c = __builtin_amdgcn_mfma_f32_16x16x32_bf16(ah[mi], bl[nt], c, 0, 0, 0);
                    acc[mi][nt] = c;
                }
            ah[0] = nh0; ah[1] = nh1; al[0] = nl0; al[1] = nl1;
        }
    }

    // ---- part 2: A = AGG (bf16 hi/lo row-major, K = 256) ----
    if (B2h) {
        const unsigned short* ah0p = AGh + (size_t)(m0 + fr) * H_DIM + fq * 8;
        const unsigned short* ah1p = AGh + (size_t)(m0 + 16 + fr) * H_DIM + fq * 8;
        const unsigned short* al0p = AGl + (size_t)(m0 + fr) * H_DIM + fq * 8;
        const unsigned short* al1p = AGl + (size_t)(m0 + 16 + fr) * H_DIM + fq * 8;
        short8 ah[2], al[2];
        ah[0] = *(const short8*)ah0p;
        ah[1] = *(const short8*)ah1p;
        al[0] = *(const short8*)al0p;
        al[1] = *(const short8*)al1p;
        #pragma unroll 1
        for (int kp = 0; kp < 8; ++kp) {
            const int kpn = (kp + 1 < 8) ? kp + 1 : kp;
            short8 nh0 = *(const short8*)(ah0p + kpn * 32);
            short8 nh1 = *(const short8*)(ah1p + kpn * 32);
            short8 nl0 = *(const short8*)(al0p + kpn * 32);
            short8 nl1 = *(const short8*)(al1p + kpn * 32);
            short8 bh[4], bl[4];
            #pragma unroll
            for (int nt = 0; nt < 4; ++nt) {
                size_t off = ((size_t)((rtbase + nt) * 8 + kp) * 64 + lane) * 8;
                bh[nt] = *(const short8*)(B2h + off);
                bl[nt] = *(const short8*)(B2l + off);
            }
            #pragma unroll
            for (int mi = 0; mi < 2; ++mi)
                #pragma unroll
                for (int nt = 0; nt < 4; ++nt) {
                    f32x4 c = acc[mi][nt];
                    c = __builtin_amdgcn_mfma_f32_16x16x32_bf16(ah[mi], bh[nt], c, 0, 0, 0);
                    c = __builtin_amdgcn_mfma_f32_16x16x32_bf16(al[mi], bh[nt], c, 0, 0, 0);
                    c = __builtin_amdgcn_mfma_f32_16x16x32_bf16(ah[mi], bl[nt], c, 0, 0, 0);
                    acc[mi][nt] = c;
                }
            ah[0] = nh0; ah[1] = nh1; al[0] = nl0; al[1] = nl1;
        }
    }

    // ---- epilogue ----
    const float leak = leak_ptr[0], il = 1.0f - leak;
    #pragma unroll
    for (int mi = 0; mi < 2; ++mi)
        #pragma unroll
        for (int r = 0; r < 4; ++r) {
            int m = m0 + mi * 16 + fq * 4 + r;
            #pragma unroll
            for (int nt = 0; nt < 4; ++nt) {
                int n = wn + nt * 16 + fr;
                size_t idx = (size_t)m * H_DIM + n;
                float old = bf2f(sphi[idx]) + bf2f(splo[idx]);
                float pre = acc[mi][nt][r];
                float e = __expf(2.0f * pre);
                float th = 1.0f - 2.0f / (e + 1.0f);
                float val = leak * th + il * old;
                unsigned short hh, ll;
                split2(val, hh, ll);
                snhi[idx] = hh;
                snlo[idx] = ll;
                int q = __float2int_rn(val * 32768.0f);
                q = q > 32767 ? 32767 : (q < -32767 ? -32767 : q);
                sncm[(size_t)(n >> 5) * NC32 + (size_t)m * 32 + (n & 31)] = (short)q;
                if (dout) dout[idx] = val;
            }
        }
}

__global__ __launch_bounds__(256) void upd_kernel(
        const unsigned short* __restrict__ Aha, const unsigned short* __restrict__ Ala, int Ka,
        const unsigned short* __restrict__ spha, const unsigned short* __restrict__ spla,
        const unsigned short* __restrict__ B1ha, const unsigned short* __restrict__ B1la,
        const unsigned short* __restrict__ B2ha, const unsigned short* __restrict__ B2la,
        const unsigned short* __restrict__ AGha, const unsigned short* __restrict__ AGla,
        unsigned short* __restrict__ snha, unsigned short* __restrict__ snla,
        short* __restrict__ scma, float* __restrict__ douta,
        const unsigned short* __restrict__ Ahb, const unsigned short* __restrict__ Alb, int Kb,
        const unsigned short* __restrict__ sphb, const unsigned short* __restrict__ splb,
        const unsigned short* __restrict__ B1hb, const unsigned short* __restrict__ B1lb,
        const unsigned short* __restrict__ B2hb, const unsigned short* __restrict__ B2lb,
        const unsigned short* __restrict__ AGhb, const unsigned short* __restrict__ AGlb,
        unsigned short* __restrict__ snhb, unsigned short* __restrict__ snlb,
        short* __restrict__ scmb, float* __restrict__ doutb,
        const float* __restrict__ leak_ptr, int merged) {
    if (merged) {
        const int task = blockIdx.x & 1;
        const int m0 = (blockIdx.x >> 1) * 32;
        if (task == 0)
            upd_body(Aha, Ala, Ka, spha, spla, B1ha, B1la, B2ha, B2la,
                     AGha, AGla, snha, snla, scma, douta, leak_ptr, m0);
        else
            upd_body(Ahb, Alb, Kb, sphb, splb, B1hb, B1lb, B2hb, B2lb,
                     AGhb, AGlb, snhb, snlb, scmb, doutb, leak_ptr, m0);
    } else {
        upd_body(Aha, Ala, Ka, spha, spla, B1ha, B1la, B2ha, B2la,
                 AGha, AGla, snha, snla, scma, douta, leak_ptr, blockIdx.x * 32);
    }
}

// ---------------- launch ----------------

extern "C" void kernel_launch(void* const* d_in, const int* in_sizes, int n_in,
                              void* d_out, int out_size, void* d_ws, size_t ws_size,
                              hipStream_t stream) {
    const float* x        = (const float*)d_in[0];
    const int*   edge     = (const int*)d_in[1];
    const float* w_in0    = (const float*)d_in[2];
    const float* w_rec0   = (const float*)d_in[3];
    const float* w_in1    = (const float*)d_in[4];
    const float* w_rec1   = (const float*)d_in[5];
    const float* leak_ptr = (const float*)d_in[6];

    const int* src = edge;
    const int* dst = edge + E_EDGES;

    char* ws = (char*)d_ws;
    size_t off = 0;
    auto alloc = [&](size_t bytes) -> char* {
        char* p = ws + off;
        off += (bytes + 255) & ~(size_t)255;
        return p;
    };
    const size_t sh_bytes = (size_t)N_NODES * H_DIM * sizeof(unsigned short);  // 10.24 MB
    const size_t x_bytes  = (size_t)T_STEPS * N_NODES * F_IN * sizeof(unsigned short);

    // bf16 hi/lo row-major state, ping-pong; int16 Q15 chunk-major gather
    // copies; AGG as bf16 hi/lo row-major.
    unsigned short* s0h[2]; unsigned short* s0l[2];
    unsigned short* s1h[2]; unsigned short* s1l[2];
    s0h[0] = (unsigned short*)alloc(sh_bytes);
    s0h[1] = (unsigned short*)alloc(sh_bytes);
    s0l[0] = (unsigned short*)alloc(sh_bytes);
    s0l[1] = (unsigned short*)alloc(sh_bytes);
    s1h[0] = (unsigned short*)alloc(sh_bytes);
    s1h[1] = (unsigned short*)alloc(sh_bytes);
    s1l[0] = (unsigned short*)alloc(sh_bytes);
    s1l[1] = (unsigned short*)alloc(sh_bytes);
    short* s0cm = (short*)alloc(sh_bytes);
    short* s1cm = (short*)alloc(sh_bytes);
    unsigned short* AG0h = (unsigned short*)alloc(sh_bytes);
    unsigned short* AG0l = (unsigned short*)alloc(sh_bytes);
    unsigned short* AG1h = (unsigned short*)alloc(sh_bytes);
    unsigned short* AG1l = (unsigned short*)alloc(sh_bytes);
    unsigned short* xh   = (unsigned short*)alloc(x_bytes);   // 41 MB
    unsigned short* xl   = (unsigned short*)alloc(x_bytes);
    unsigned short* w0h  = (unsigned short*)alloc(256 * 128 * 2);
    unsigned short* w0l  = (unsigned short*)alloc(256 * 128 * 2);
    unsigned short* wr0h = (unsigned short*)alloc(256 * 256 * 2);
    unsigned short* wr0l = (unsigned short*)alloc(256 * 256 * 2);
    unsigned short* w1h  = (unsigned short*)alloc(256 * 256 * 2);
    unsigned short* w1l  = (unsigned short*)alloc(256 * 256 * 2);
    unsigned short* wr1h = (unsigned short*)alloc(256 * 256 * 2);
    unsigned short* wr1l = (unsigned short*)alloc(256 * 256 * 2);
    int* row_ptr = (int*)alloc((N_NODES + 1) * sizeof(int));
    int* cursors = (int*)alloc(N_NODES * sizeof(int));
    int* counts  = (int*)alloc(N_NODES * sizeof(int));
    unsigned short* col = (unsigned short*)alloc((size_t)E_EDGES * sizeof(unsigned short));

    hipMemsetAsync(s0h[0], 0, sh_bytes, stream);
    hipMemsetAsync(s0l[0], 0, sh_bytes, stream);
    hipMemsetAsync(s1h[0], 0, sh_bytes, stream);
    hipMemsetAsync(s1l[0], 0, sh_bytes, stream);
    hipMemsetAsync(counts, 0, N_NODES * sizeof(int), stream);

    cvt_frag<<<16, 256, 0, stream>>>(w_in0, F_IN, w0h, w0l);
    cvt_frag<<<32, 256, 0, stream>>>(w_rec0, H_DIM, wr0h, wr0l);
    cvt_frag<<<32, 256, 0, stream>>>(w_in1, H_DIM, w1h, w1l);
    cvt_frag<<<32, 256, 0, stream>>>(w_rec1, H_DIM, wr1h, wr1l);
    cvt_split<<<20000, 256, 0, stream>>>(x, xh, xl, T_STEPS * N_NODES * F_IN / 4);

    count_kernel<<<(E_EDGES + 255) / 256, 256, 0, stream>>>(dst, counts, E_EDGES);
    scan_kernel<<<1, 1024, 0, stream>>>(counts, row_ptr, cursors, N_NODES);
    fill_kernel<<<(E_EDGES + 255) / 256, 256, 0, stream>>>(src, dst, cursors, col, E_EDGES);

    dim3 g_upd1(G_UPD);      // 625
    dim3 g_upd2(2 * G_UPD);  // 1250 merged
    dim3 g_agg1(G_AGG);      // 5000
    dim3 g_agg2(2 * G_AGG);  // 10000 dual-buffer

    const size_t xstep = (size_t)N_NODES * F_IN;

    // Schedule (s0(t) in slot (t+1)&1, s1(t) in slot (t+1)&1):
    //   UPD0(0); AGG(s0cm -> AG0)
    //   t = 0..6: UPDm(t) = UPD1(t)+UPD0(t+1); AGG dual s1cm->AG1, s0cm->AG0
    //   UPD1(7) -> d_out (f32)

    // UPD0(0): A = x(0) presplit, no AGG
    upd_kernel<<<g_upd1, 256, 0, stream>>>(
        xh, xl, F_IN, s0h[0], s0l[0], w0h, w0l, nullptr, nullptr,
        nullptr, nullptr, s0h[1], s0l[1], s0cm, nullptr,
        nullptr, nullptr, 0, nullptr, nullptr, nullptr, nullptr, nullptr, nullptr,
        nullptr, nullptr, nullptr, nullptr, nullptr, nullptr,
        leak_ptr, 0);
    agg_kernel<<<g_agg1, 256, 0, stream>>>(s0cm, AG0h, AG0l,
                                           nullptr, nullptr, nullptr, row_ptr, col);

    for (int t = 0; t < 7; ++t) {
        unsigned short* s0th = s0h[(t + 1) & 1];  // s0(t)
        unsigned short* s0tl = s0l[(t + 1) & 1];
        unsigned short* s0nh = s0h[t & 1];        // s0(t+1) dest
        unsigned short* s0nl = s0l[t & 1];
        unsigned short* s1ph = s1h[t & 1];        // s1(t-1)
        unsigned short* s1pl = s1l[t & 1];
        unsigned short* s1th = s1h[(t + 1) & 1];  // s1(t) dest
        unsigned short* s1tl = s1l[(t + 1) & 1];
        int dg1 = (t > 0) ? 1 : 0;                // s1(-1)=0 -> skip AGG term

        // UPDm(t): task a = UPD1(t), task b = UPD0(t+1)
        upd_kernel<<<g_upd2, 256, 0, stream>>>(
            s0th, s0tl, H_DIM, s1ph, s1pl, w1h, w1l,
            dg1 ? wr1h : nullptr, dg1 ? wr1l : nullptr,
            AG1h, AG1l, s1th, s1tl, s1cm, nullptr,
            xh + (size_t)(t + 1) * xstep, xl + (size_t)(t + 1) * xstep, F_IN,
            s0th, s0tl, w0h, w0l, wr0h, wr0l,
            AG0h, AG0l, s0nh, s0nl, s0cm, nullptr,
            leak_ptr, 1);

        if (t < 6) {
            agg_kernel<<<g_agg2, 256, 0, stream>>>(s1cm, AG1h, AG1l,
                                                   s0cm, AG0h, AG0l, row_ptr, col);
        } else {
            agg_kernel<<<g_agg1, 256, 0, stream>>>(s1cm, AG1h, AG1l,
                                                   nullptr, nullptr, nullptr, row_ptr, col);
        }
    }

    // UPD1(7): A = s0(7) = slot 0, sp = s1(6) = slot 1, dout = d_out
    upd_kernel<<<g_upd1, 256, 0, stream>>>(
        s0h[0], s0l[0], H_DIM, s1h[1], s1l[1], w1h, w1l, wr1h, wr1l,
        AG1h, AG1l, s1h[0], s1l[0], s1cm, (float*)d_out,
        nullptr, nullptr, 0, nullptr, nullptr, nullptr, nullptr, nullptr, nullptr,
        nullptr, nullptr, nullptr, nullptr, nullptr, nullptr,
        leak_ptr, 0);
}